// Round 12
// baseline (159.246 us; speedup 1.0000x reference)
//
#include <hip/hip_runtime.h>
#include <math.h>

#define NREG  8
#define HDIM  128
#define NDEPTH 3
#define TP    64      // points per workgroup tile
#define W0F   30.0f

// ---------------- routing helpers ----------------

__device__ __forceinline__ int region_of(float X, float Y, float Z, bool* valid) {
    *valid = (X >= 0.f) & (X <= 1.f) & (Y >= 0.f) & (Y <= 1.f) & (Z >= 0.f) & (Z <= 1.f);
    // box r = i*4 + j*2 + k ; ties at 0.5 belong to the lower box (argmax picks first)
    int i = (X > 0.5f) ? 1 : 0;
    int j = (Y > 0.5f) ? 1 : 0;
    int k = (Z > 0.5f) ? 1 : 0;
    return i * 4 + j * 2 + k;
}

// ws int layout: [0..7] counts, [8..16] offsets(exclusive, +total), [20..27] cursors
__global__ __launch_bounds__(256) void k_count(const float* __restrict__ x, int n,
                                               int* __restrict__ ws) {
    __shared__ int h[NREG];
    if (threadIdx.x < NREG) h[threadIdx.x] = 0;
    __syncthreads();
    int i = blockIdx.x * 256 + threadIdx.x;
    if (i < n) {
        float X = x[3*i], Y = x[3*i+1], Z = x[3*i+2];
        bool valid;
        int r = region_of(X, Y, Z, &valid);
        if (valid) atomicAdd(&h[r], 1);
    }
    __syncthreads();
    if (threadIdx.x < NREG) atomicAdd(&ws[threadIdx.x], h[threadIdx.x]);
}

__global__ void k_prefix(int* __restrict__ ws) {
    if (threadIdx.x == 0) {
        int acc = 0;
        for (int r = 0; r < NREG; ++r) {
            ws[8 + r] = acc;      // offsets
            ws[20 + r] = acc;     // cursors
            acc += ws[r];
        }
        ws[8 + NREG] = acc;
    }
}

// Block-aggregated scatter: LDS-rank within block, ONE global atomic per
// (block, region) chunk reservation, then direct stores.
__global__ __launch_bounds__(256) void k_scatter(const float* __restrict__ x, int n,
                                                 int* __restrict__ ws,
                                                 int* __restrict__ idx,
                                                 float* __restrict__ out) {
    __shared__ int hist[NREG];
    __shared__ int base[NREG];
    const int tid = threadIdx.x;
    if (tid < NREG) hist[tid] = 0;
    __syncthreads();
    int i = blockIdx.x * 256 + tid;
    int r = 0, rank = 0;
    bool valid = false;
    if (i < n) {
        float X = x[3*i], Y = x[3*i+1], Z = x[3*i+2];
        r = region_of(X, Y, Z, &valid);
        if (valid) rank = atomicAdd(&hist[r], 1);   // within-block rank
        else out[i] = 0.0f;   // points outside all boxes stay zero
    }
    __syncthreads();
    if (tid < NREG) {
        int c = hist[tid];
        base[tid] = c ? atomicAdd(&ws[20 + tid], c) : 0;
    }
    __syncthreads();
    if (valid) idx[base[r] + rank] = i;
}

// ---------------- fused per-region SIREN MLP ----------------
// r10 structure (acts: 1 ds_read_b128/thread/j; weights: VMEM float4,
// L2-resident) + explicit 2-deep register pipeline: prefetch j-pair g+1
// (weights AND activations) before computing pair g. Static double-buffer
// via #pragma unroll 2 + (g&1) branch (rule #20: no dynamic reg indexing).
// r10 post-mortem: unroll-4 window exposed ~200cyc L2 latency every group
// (VALUBusy 42%); prefetch spans groups -> latency hidden under 128 FMA cyc.

#define LOADW(jbase, WA, WB) do {                                  \
    const float* w0_ = Wl + (size_t)(jbase) * HDIM;                \
    WA[0] = *(const float4*)(w0_);                                 \
    WB[0] = *(const float4*)(w0_ + 4);                             \
    WA[1] = *(const float4*)(w0_ + HDIM);                          \
    WB[1] = *(const float4*)(w0_ + HDIM + 4);                      \
  } while (0)

#define LOADA(jbase, AA) do {                                      \
    AA[0] = *(const float4*)&hA[(jbase)][p0];                      \
    AA[1] = *(const float4*)&hA[(jbase) + 1][p0];                  \
  } while (0)

#define COMPUTE(WA, WB, AA) do {                                   \
    _Pragma("unroll")                                              \
    for (int jj = 0; jj < 2; ++jj) {                               \
      float av_[4] = {AA[jj].x, AA[jj].y, AA[jj].z, AA[jj].w};     \
      float wv_[8] = {WA[jj].x, WA[jj].y, WA[jj].z, WA[jj].w,      \
                      WB[jj].x, WB[jj].y, WB[jj].z, WB[jj].w};     \
      _Pragma("unroll")                                            \
      for (int m = 0; m < 4; ++m)                                  \
        _Pragma("unroll")                                          \
        for (int kc = 0; kc < 8; ++kc)                             \
          acc[m][kc] = fmaf(av_[m], wv_[kc], acc[m][kc]);          \
    }                                                              \
  } while (0)

__global__ __launch_bounds__(256) void k_mlp(
    const float* __restrict__ x,
    const float* __restrict__ W_in,  const float* __restrict__ b_in,
    const float* __restrict__ W_h,   const float* __restrict__ b_h,
    const float* __restrict__ W_out, const float* __restrict__ b_out,
    const float* __restrict__ scale, const float* __restrict__ boxes,
    const int* __restrict__ offsets, const int* __restrict__ idx,
    float* __restrict__ out)
{
    __shared__ __align__(16) float hA[HDIM][TP];   // 32 KB [channel][point]
    __shared__ float part[4][TP];
    __shared__ float xn_s[TP][3];
    __shared__ int   gidx[TP];

    const int tid = threadIdx.x;

    // map flat block id -> (region, tile)
    int r = -1, base = 0, cnt = 0;
    {
        int bid = blockIdx.x, acc0 = 0;
        for (int rr = 0; rr < NREG; ++rr) {
            int o0 = offsets[rr], o1 = offsets[rr + 1];
            int c = o1 - o0;
            int t = (c + TP - 1) / TP;
            if (bid < acc0 + t) {
                int tile = bid - acc0;
                r = rr; base = o0 + tile * TP; cnt = c - tile * TP;
                break;
            }
            acc0 += t;
        }
    }
    if (r < 0) return;                 // uniform across the block
    if (cnt > TP) cnt = TP;

    // ---- stage points (normalized coords) + gather indices ----
    if (tid < TP) {
        int g = (tid < cnt) ? idx[base + tid] : -1;
        gidx[tid] = g;
        float xs[3] = {0.f, 0.f, 0.f};
        if (g >= 0) { xs[0] = x[3*g]; xs[1] = x[3*g+1]; xs[2] = x[3*g+2]; }
        #pragma unroll
        for (int d = 0; d < 3; ++d) {
            float lo = boxes[r*6 + d*2 + 0];
            float hi = boxes[r*6 + d*2 + 1];
            float xn = (2.0f * (xs[d] - lo) / (hi - lo) - 1.0f) * scale[r*3 + d];
            xn_s[tid][d] = (g >= 0) ? xn : 0.0f;
        }
    }
    __syncthreads();

    const int pg  = tid & 15;      // 16 point-groups x 4 pts
    const int kg  = tid >> 4;      // 16 channel-groups x 8 ch
    const int p0  = pg * 4;
    const int k0c = kg * 8;

    // ---- input layer: h = sin(30*(xn @ W_in + b_in)) ----
    {
        const float* Wr = W_in + r * 3 * HDIM;
        const float* br = b_in + r * HDIM;
        float xm[4][3];
        #pragma unroll
        for (int m = 0; m < 4; ++m) {
            xm[m][0] = xn_s[p0 + m][0];
            xm[m][1] = xn_s[p0 + m][1];
            xm[m][2] = xn_s[p0 + m][2];
        }
        #pragma unroll
        for (int kc = 0; kc < 8; ++kc) {
            int k = k0c + kc;
            float w0 = Wr[0 * HDIM + k];
            float w1 = Wr[1 * HDIM + k];
            float w2 = Wr[2 * HDIM + k];
            float bk = br[k];
            float v[4];
            #pragma unroll
            for (int m = 0; m < 4; ++m) {
                float a = fmaf(xm[m][0], w0, fmaf(xm[m][1], w1, fmaf(xm[m][2], w2, bk)));
                v[m] = sinf(W0F * a);
            }
            *(float4*)&hA[k][p0] = make_float4(v[0], v[1], v[2], v[3]);
        }
    }
    __syncthreads();

    // ---- hidden layers (2-deep pipelined over j-pairs) ----
    for (int l = 0; l < NDEPTH; ++l) {
        const float* Wl = W_h + ((size_t)(r * NDEPTH + l)) * HDIM * HDIM + k0c;
        const float* bl = b_h + (r * NDEPTH + l) * HDIM + k0c;
        float acc[4][8];
        #pragma unroll
        for (int m = 0; m < 4; ++m)
            #pragma unroll
            for (int kc = 0; kc < 8; ++kc) acc[m][kc] = 0.f;

        float4 wAa[2], wBa[2], aAa[2];   // buffer A: j-pair
        float4 wAb[2], wBb[2], aAb[2];   // buffer B: j-pair

        LOADW(0, wAa, wBa);
        LOADA(0, aAa);

        #pragma unroll 2
        for (int g = 0; g < HDIM / 2; ++g) {   // 64 j-pairs
            int j = g * 2;
            if ((g & 1) == 0) {
                if (g < HDIM / 2 - 1) { LOADW(j + 2, wAb, wBb); LOADA(j + 2, aAb); }
                COMPUTE(wAa, wBa, aAa);
            } else {
                if (g < HDIM / 2 - 1) { LOADW(j + 2, wAa, wBa); LOADA(j + 2, aAa); }
                COMPUTE(wAb, wBb, aAb);
            }
        }

        // bias + sin in registers
        float4 bA = *(const float4*)(bl);
        float4 bB = *(const float4*)(bl + 4);
        float bb[8] = {bA.x, bA.y, bA.z, bA.w, bB.x, bB.y, bB.z, bB.w};
        float v[4][8];
        #pragma unroll
        for (int m = 0; m < 4; ++m)
            #pragma unroll
            for (int kc = 0; kc < 8; ++kc)
                v[m][kc] = sinf(W0F * (acc[m][kc] + bb[kc]));

        __syncthreads();   // all waves finished reading hA for this layer
        #pragma unroll
        for (int kc = 0; kc < 8; ++kc)
            *(float4*)&hA[k0c + kc][p0] = make_float4(v[0][kc], v[1][kc], v[2][kc], v[3][kc]);
        __syncthreads();   // writes visible before next layer reads
    }

    // ---- output layer: per-wave partial dot over 32 channels ----
    {
        const int wv_  = tid >> 6;        // wave id 0..3
        const int lane = tid & 63;        // point
        const int k0w  = wv_ * 32;
        const float* Wo = W_out + r * HDIM + k0w;
        float s = 0.f;
        #pragma unroll 8
        for (int c = 0; c < 32; ++c)
            s = fmaf(hA[k0w + c][lane], Wo[c], s);
        part[wv_][lane] = s;
        __syncthreads();
        if (wv_ == 0) {
            float o = part[0][lane] + part[1][lane] + part[2][lane] + part[3][lane]
                    + b_out[r];
            int g = gidx[lane];
            if (g >= 0) out[g] = o;
        }
    }
}

// ---------------- launcher ----------------

extern "C" void kernel_launch(void* const* d_in, const int* in_sizes, int n_in,
                              void* d_out, int out_size, void* d_ws, size_t ws_size,
                              hipStream_t stream) {
    const float* x      = (const float*)d_in[0];
    const float* W_in   = (const float*)d_in[1];
    const float* b_in   = (const float*)d_in[2];
    const float* W_h    = (const float*)d_in[3];
    const float* b_h    = (const float*)d_in[4];
    const float* W_out  = (const float*)d_in[5];
    const float* b_out  = (const float*)d_in[6];
    const float* scale  = (const float*)d_in[7];
    const float* boxes  = (const float*)d_in[8];
    float* out = (float*)d_out;

    int n = in_sizes[0] / 3;
    int* wsi = (int*)d_ws;
    int* idx = (int*)((char*)d_ws + 256);

    hipMemsetAsync(d_ws, 0, 256, stream);

    int nb = (n + 255) / 256;
    hipLaunchKernelGGL(k_count,   dim3(nb), dim3(256), 0, stream, x, n, wsi);
    hipLaunchKernelGGL(k_prefix,  dim3(1),  dim3(64),  0, stream, wsi);
    hipLaunchKernelGGL(k_scatter, dim3(nb), dim3(256), 0, stream, x, n, wsi, idx, out);

    int ntiles = (n + TP - 1) / TP + NREG;
    hipLaunchKernelGGL(k_mlp, dim3(ntiles), dim3(256), 0, stream,
                       x, W_in, b_in, W_h, b_h, W_out, b_out, scale, boxes,
                       wsi + 8, idx, out);
}

// Round 13
// 149.416 us; speedup vs baseline: 1.0658x; 1.0658x over previous
//
#include <hip/hip_runtime.h>
#include <math.h>

#define NREG  8
#define HDIM  128
#define NDEPTH 3
#define TP    64      // points per workgroup tile (= lanes per wave)
#define W0F   30.0f

// ---------------- routing helpers ----------------

__device__ __forceinline__ int region_of(float X, float Y, float Z, bool* valid) {
    *valid = (X >= 0.f) & (X <= 1.f) & (Y >= 0.f) & (Y <= 1.f) & (Z >= 0.f) & (Z <= 1.f);
    // box r = i*4 + j*2 + k ; ties at 0.5 belong to the lower box (argmax picks first)
    int i = (X > 0.5f) ? 1 : 0;
    int j = (Y > 0.5f) ? 1 : 0;
    int k = (Z > 0.5f) ? 1 : 0;
    return i * 4 + j * 2 + k;
}

// ws int layout: [0..7] counts, [8..16] offsets(exclusive, +total), [20..27] cursors
__global__ __launch_bounds__(256) void k_count(const float* __restrict__ x, int n,
                                               int* __restrict__ ws) {
    __shared__ int h[NREG];
    if (threadIdx.x < NREG) h[threadIdx.x] = 0;
    __syncthreads();
    int i = blockIdx.x * 256 + threadIdx.x;
    if (i < n) {
        float X = x[3*i], Y = x[3*i+1], Z = x[3*i+2];
        bool valid;
        int r = region_of(X, Y, Z, &valid);
        if (valid) atomicAdd(&h[r], 1);
    }
    __syncthreads();
    if (threadIdx.x < NREG) atomicAdd(&ws[threadIdx.x], h[threadIdx.x]);
}

__global__ void k_prefix(int* __restrict__ ws) {
    if (threadIdx.x == 0) {
        int acc = 0;
        for (int r = 0; r < NREG; ++r) {
            ws[8 + r] = acc;      // offsets
            ws[20 + r] = acc;     // cursors
            acc += ws[r];
        }
        ws[8 + NREG] = acc;
    }
}

// Block-aggregated scatter: LDS-rank within block, ONE global atomic per
// (block, region) chunk reservation, then direct stores.
__global__ __launch_bounds__(256) void k_scatter(const float* __restrict__ x, int n,
                                                 int* __restrict__ ws,
                                                 int* __restrict__ idx,
                                                 float* __restrict__ out) {
    __shared__ int hist[NREG];
    __shared__ int base[NREG];
    const int tid = threadIdx.x;
    if (tid < NREG) hist[tid] = 0;
    __syncthreads();
    int i = blockIdx.x * 256 + tid;
    int r = 0, rank = 0;
    bool valid = false;
    if (i < n) {
        float X = x[3*i], Y = x[3*i+1], Z = x[3*i+2];
        r = region_of(X, Y, Z, &valid);
        if (valid) rank = atomicAdd(&hist[r], 1);   // within-block rank
        else out[i] = 0.0f;   // points outside all boxes stay zero
    }
    __syncthreads();
    if (tid < NREG) {
        int c = hist[tid];
        base[tid] = c ? atomicAdd(&ws[20 + tid], c) : 0;
    }
    __syncthreads();
    if (valid) idx[base[r] + rank] = i;
}

// ---------------- fused per-region SIREN MLP ----------------
// r3 structure WITHOUT the VGPR cap (r3's only failure was __launch_bounds__
// (256,4) -> 64-VGPR cap -> acc[32] spilled, 68MB scratch).
// lane = point, wave = 32-channel chunk. Activations hA[128][64] in LDS;
// per j: ONE conflict-free ds_read_b32 per wave (hA[j][lane], stride-1,
// 2-way bank alias = free). Weights: k0 forced wave-uniform via
// readfirstlane -> Wl[j*128+k0+c] is provably uniform -> s_load_dwordx16
// on the SCALAR pipe (K$-cached, zero VALU/VMEM issue cost).
// Inner loop per j = 32 x v_fmac_f32(vacc, s_w, v_a): ~pure FMA issue.
// r10/r12 post-mortem: VMEM-float4 variants spent ~50% of VALU issue on
// address arith + unpack moves (90us issue vs 41us useful FMA content).

__global__ __launch_bounds__(256) void k_mlp(
    const float* __restrict__ x,
    const float* __restrict__ W_in,  const float* __restrict__ b_in,
    const float* __restrict__ W_h,   const float* __restrict__ b_h,
    const float* __restrict__ W_out, const float* __restrict__ b_out,
    const float* __restrict__ scale, const float* __restrict__ boxes,
    const int* __restrict__ offsets, const int* __restrict__ idx,
    float* __restrict__ out)
{
    __shared__ __align__(16) float hA[HDIM][TP];   // 32 KB [channel][point]
    __shared__ float part[4][TP];

    const int tid  = threadIdx.x;
    const int wv   = tid >> 6;      // wave id 0..3 -> channel chunk
    const int lane = tid & 63;      // point within tile
    const int k0   = __builtin_amdgcn_readfirstlane(wv << 5);  // SGPR chunk base

    // map flat block id -> (region, tile)
    int r = -1, base = 0, cnt = 0;
    {
        int bid = blockIdx.x, acc0 = 0;
        for (int rr = 0; rr < NREG; ++rr) {
            int o0 = offsets[rr], o1 = offsets[rr + 1];
            int c = o1 - o0;
            int t = (c + TP - 1) / TP;
            if (bid < acc0 + t) {
                int tile = bid - acc0;
                r = rr; base = o0 + tile * TP; cnt = c - tile * TP;
                break;
            }
            acc0 += t;
        }
    }
    if (r < 0) return;                 // uniform across the block
    if (cnt > TP) cnt = TP;

    // ---- per-lane point & normalized coords ----
    int g = (lane < cnt) ? idx[base + lane] : -1;
    float xn0 = 0.f, xn1 = 0.f, xn2 = 0.f;
    if (g >= 0) {
        float lo0 = boxes[r*6 + 0], hi0 = boxes[r*6 + 1];
        float lo1 = boxes[r*6 + 2], hi1 = boxes[r*6 + 3];
        float lo2 = boxes[r*6 + 4], hi2 = boxes[r*6 + 5];
        xn0 = (2.0f * (x[3*g+0] - lo0) / (hi0 - lo0) - 1.0f) * scale[r*3 + 0];
        xn1 = (2.0f * (x[3*g+1] - lo1) / (hi1 - lo1) - 1.0f) * scale[r*3 + 1];
        xn2 = (2.0f * (x[3*g+2] - lo2) / (hi2 - lo2) - 1.0f) * scale[r*3 + 2];
    }

    // ---- input layer: hA[k][lane] = sin(30*(xn . W_in[:,k] + b_in[k])) ----
    {
        const float* Wr = W_in + r * 3 * HDIM + k0;   // uniform base -> s_load
        const float* br = b_in + r * HDIM + k0;
        #pragma unroll 8
        for (int c = 0; c < 32; ++c) {
            float pre = fmaf(xn0, Wr[0*HDIM + c],
                        fmaf(xn1, Wr[1*HDIM + c],
                        fmaf(xn2, Wr[2*HDIM + c], br[c])));
            hA[k0 + c][lane] = sinf(W0F * pre);
        }
    }
    __syncthreads();

    // ---- hidden layers ----
    for (int l = 0; l < NDEPTH; ++l) {
        const float* Wl = W_h + ((size_t)(r * NDEPTH + l)) * HDIM * HDIM + k0;
        const float* bl = b_h + (r * NDEPTH + l) * HDIM + k0;
        float acc[32];
        #pragma unroll
        for (int c = 0; c < 32; ++c) acc[c] = bl[c];   // bias-init (scalar load)

        #pragma unroll 2
        for (int j = 0; j < HDIM; ++j) {
            float a = hA[j][lane];                      // 1 ds_read_b32 / wave / j
            const float* wrow = Wl + (size_t)j * HDIM;  // uniform row -> s_load
            #pragma unroll
            for (int c = 0; c < 32; ++c)
                acc[c] = fmaf(wrow[c], a, acc[c]);      // v_fmac with SGPR weight
        }
        // sin in registers, then in-place overwrite of hA
        #pragma unroll
        for (int c = 0; c < 32; ++c) acc[c] = sinf(W0F * acc[c]);
        __syncthreads();   // all waves finished reading hA
        #pragma unroll
        for (int c = 0; c < 32; ++c) hA[k0 + c][lane] = acc[c];
        __syncthreads();   // writes visible before next layer reads
    }

    // ---- output layer: partial dot per wave chunk, reduce via LDS ----
    {
        const float* Wo = W_out + r * HDIM + k0;       // uniform -> s_load
        float s = 0.f;
        #pragma unroll 8
        for (int c = 0; c < 32; ++c)
            s = fmaf(Wo[c], hA[k0 + c][lane], s);
        part[wv][lane] = s;
    }
    __syncthreads();
    if (wv == 0) {
        float s = part[0][lane] + part[1][lane] + part[2][lane] + part[3][lane]
                + b_out[r];
        if (g >= 0) out[g] = s;
    }
}

// ---------------- launcher ----------------

extern "C" void kernel_launch(void* const* d_in, const int* in_sizes, int n_in,
                              void* d_out, int out_size, void* d_ws, size_t ws_size,
                              hipStream_t stream) {
    const float* x      = (const float*)d_in[0];
    const float* W_in   = (const float*)d_in[1];
    const float* b_in   = (const float*)d_in[2];
    const float* W_h    = (const float*)d_in[3];
    const float* b_h    = (const float*)d_in[4];
    const float* W_out  = (const float*)d_in[5];
    const float* b_out  = (const float*)d_in[6];
    const float* scale  = (const float*)d_in[7];
    const float* boxes  = (const float*)d_in[8];
    float* out = (float*)d_out;

    int n = in_sizes[0] / 3;
    int* wsi = (int*)d_ws;
    int* idx = (int*)((char*)d_ws + 256);

    hipMemsetAsync(d_ws, 0, 256, stream);

    int nb = (n + 255) / 256;
    hipLaunchKernelGGL(k_count,   dim3(nb), dim3(256), 0, stream, x, n, wsi);
    hipLaunchKernelGGL(k_prefix,  dim3(1),  dim3(64),  0, stream, wsi);
    hipLaunchKernelGGL(k_scatter, dim3(nb), dim3(256), 0, stream, x, n, wsi, idx, out);

    int ntiles = (n + TP - 1) / TP + NREG;
    hipLaunchKernelGGL(k_mlp, dim3(ntiles), dim3(256), 0, stream,
                       x, W_in, b_in, W_h, b_h, W_out, b_out, scale, boxes,
                       wsi + 8, idx, out);
}